// Round 1
// baseline (1224.931 us; speedup 1.0000x reference)
//
#include <hip/hip_runtime.h>
#include <hip/hip_bf16.h>

// MoE top-2: T=8192 tokens, D=1024, F=4096, E=8.
// Pipeline: transpose-cast weights -> router -> gather -> GEMM1(gelu) -> GEMM2(scatter-add).

#define T_TOK 8192
#define DDIM  1024
#define FDIM  4096
#define NEXP  8
#define RTOT  (T_TOK * 2)      // total assigned rows (top-2, always exactly 2T)
#define RPAD  (RTOT + 128)     // slack so tile staging can over-read harmlessly

#define BM 128
#define BN 128
#define BK 64

typedef __bf16 bf16x8 __attribute__((ext_vector_type(8)));
typedef float  f32x4  __attribute__((ext_vector_type(4)));

__device__ __forceinline__ float gelu_tanh(float x) {
  // jax.nn.gelu default (approximate=True)
  float u = 0.7978845608028654f * (x + 0.044715f * x * x * x);
  return 0.5f * x * (1.0f + tanhf(u));
}

#define GLOBAL_TO_LDS16(gp, lp)                                                   \
  __builtin_amdgcn_global_load_lds((const __attribute__((address_space(1))) void*)(gp), \
                                   (__attribute__((address_space(3))) void*)(lp), 16, 0, 0)

// ---------------- transpose + cast: fp32 [E][Rr][Cc] -> bf16 [E][Cc][Rr] ----------------
__global__ __launch_bounds__(256) void transpose_cast(const float* __restrict__ in,
                                                      __hip_bfloat16* __restrict__ outp,
                                                      int Rr, int Cc) {
  __shared__ __hip_bfloat16 tile[64][65];  // +1 pad breaks bank conflicts
  int tilesR = Rr >> 6, tilesC = Cc >> 6;
  int per = tilesR * tilesC;
  int e = blockIdx.x / per, rem = blockIdx.x % per;
  int tr = rem / tilesC, tc = rem % tilesC;
  const float* ip = in + (size_t)e * Rr * Cc;
  __hip_bfloat16* op = outp + (size_t)e * Rr * Cc;
  int tx = threadIdx.x & 63, ty = threadIdx.x >> 6;  // ty in 0..3
  int r0 = tr * 64, c0 = tc * 64;
#pragma unroll 4
  for (int i = 0; i < 16; i++) {
    int r = i * 4 + ty;
    tile[r][tx] = __float2bfloat16(ip[(size_t)(r0 + r) * Cc + c0 + tx]);
  }
  __syncthreads();
#pragma unroll 4
  for (int i = 0; i < 16; i++) {
    int c = i * 4 + ty;
    op[(size_t)(c0 + c) * Rr + r0 + tx] = tile[tx][c];
  }
}

// ---------------- router: logits -> top2 -> gates + slot assignment ----------------
__global__ __launch_bounds__(256) void router_kernel(const float* __restrict__ x,
                                                     const float* __restrict__ rw,
                                                     int* __restrict__ counts,
                                                     int* __restrict__ pair_e,
                                                     int* __restrict__ pair_slot,
                                                     float* __restrict__ pair_gate) {
  int lane = threadIdx.x & 63;
  int wid = threadIdx.x >> 6;
  int t = blockIdx.x * 4 + wid;  // one wave per token
  const float* xr = x + (size_t)t * DDIM;
  float acc[NEXP];
#pragma unroll
  for (int e = 0; e < NEXP; e++) acc[e] = 0.f;
  for (int d0 = lane * 4; d0 < DDIM; d0 += 256) {
    float4 xv = *(const float4*)(xr + d0);
    const float* r0 = rw + (size_t)d0 * NEXP;
#pragma unroll
    for (int e = 0; e < NEXP; e++)
      acc[e] += xv.x * r0[e] + xv.y * r0[NEXP + e] + xv.z * r0[2 * NEXP + e] + xv.w * r0[3 * NEXP + e];
  }
#pragma unroll
  for (int e = 0; e < NEXP; e++) {
#pragma unroll
    for (int m = 32; m > 0; m >>= 1) acc[e] += __shfl_xor(acc[e], m, 64);
  }
  if (lane == 0) {
    int e1 = 0; float l1 = acc[0];
    for (int e = 1; e < NEXP; e++) if (acc[e] > l1) { l1 = acc[e]; e1 = e; }
    int e2 = -1; float l2 = -1e30f;
    for (int e = 0; e < NEXP; e++) { if (e == e1) continue; if (acc[e] > l2) { l2 = acc[e]; e2 = e; } }
    // renormalized top-2 softmax == softmax over the two logits
    float g1 = 1.f / (1.f + __expf(l2 - l1));
    float g2 = 1.f - g1;
    int s1 = atomicAdd(&counts[e1], 1);
    int s2 = atomicAdd(&counts[e2], 1);
    pair_e[2 * t] = e1;     pair_slot[2 * t] = s1;     pair_gate[2 * t] = g1;
    pair_e[2 * t + 1] = e2; pair_slot[2 * t + 1] = s2; pair_gate[2 * t + 1] = g2;
  }
}

// ---------------- gather: x rows -> expert-compacted bf16 Xg ----------------
__global__ __launch_bounds__(256) void gather_kernel(const float* __restrict__ x,
                                                     const int* __restrict__ counts,
                                                     const int* __restrict__ pair_e,
                                                     const int* __restrict__ pair_slot,
                                                     const float* __restrict__ pair_gate,
                                                     __hip_bfloat16* __restrict__ Xg,
                                                     int* __restrict__ row_token,
                                                     float* __restrict__ row_gate) {
  int p = blockIdx.x;
  int t = p >> 1;
  int e = pair_e[p];
  int base = 0;
#pragma unroll
  for (int i = 0; i < NEXP; i++) base += (i < e) ? counts[i] : 0;
  int row = base + pair_slot[p];
  const float* xr = x + (size_t)t * DDIM;
  __hip_bfloat16* dst = Xg + (size_t)row * DDIM;
  int i = threadIdx.x * 4;
  float4 v = *(const float4*)(xr + i);
  union { ushort4 u; __hip_bfloat16 h[4]; } o;
  o.h[0] = __float2bfloat16(v.x);
  o.h[1] = __float2bfloat16(v.y);
  o.h[2] = __float2bfloat16(v.z);
  o.h[3] = __float2bfloat16(v.w);
  *(ushort4*)(dst + i) = o.u;
  if (threadIdx.x == 0) { row_token[row] = t; row_gate[row] = pair_gate[p]; }
}

// ---------------- tiled bf16 MFMA GEMM, per-expert row ranges ----------------
// A: bf16 [RPAD][K] (expert-compacted rows). Bw: bf16 [E][N][K] (pre-transposed).
// EPI=0: Hout[row][N] = gelu(A@B) as bf16.  EPI=1: out[token][N] += gate * (A@B) fp32.
template <int EPI>
__global__ __launch_bounds__(256) void moe_gemm(const __hip_bfloat16* __restrict__ A,
                                                const __hip_bfloat16* __restrict__ Bw,
                                                __hip_bfloat16* __restrict__ Hout,
                                                float* __restrict__ out,
                                                const int* __restrict__ counts,
                                                const int* __restrict__ row_token,
                                                const float* __restrict__ row_gate,
                                                int K, int N) {
  const int MT = T_TOK / BM;  // worst-case m-tiles per expert
  const int NT = N / BN;
  int bid = blockIdx.x;
  int e = bid / (MT * NT);
  int rem = bid % (MT * NT);
  // supergroup swizzle: consecutive blocks share B n-slices / A m-slices for L2 reuse
  const int GM = 8;
  int width = GM * NT;
  int group = rem / width;
  int gm0 = group * GM;
  int gsize = (MT - gm0 < GM) ? (MT - gm0) : GM;
  int mt = gm0 + (rem % gsize);
  int nt = (rem % width) / gsize;

  int n_e = counts[e];
  if (mt * BM >= n_e) return;  // block beyond this expert's token count
  int row0 = 0;
  for (int i = 0; i < NEXP; i++) row0 += (i < e) ? counts[i] : 0;
  int m_start = row0 + mt * BM;
  int row_end = row0 + n_e;

  const __hip_bfloat16* Abase = A + (size_t)m_start * K;
  const __hip_bfloat16* Bbase = Bw + (size_t)e * N * K + (size_t)(nt * BN) * K;

  __shared__ alignas(16) __hip_bfloat16 As[BM * BK];
  __shared__ alignas(16) __hip_bfloat16 Bs[BN * BK];

  int tid = threadIdx.x;
  int lane = tid & 63, wid = tid >> 6;
  int wm = (wid >> 1) * 64, wn = (wid & 1) * 64;  // 2x2 wave grid, 64x64 each
  int lr = lane & 15;
  int kq = (lane >> 4) * 8;

  f32x4 acc[4][4];
#pragma unroll
  for (int i = 0; i < 4; i++)
#pragma unroll
    for (int j = 0; j < 4; j++)
#pragma unroll
      for (int r = 0; r < 4; r++) acc[i][j][r] = 0.f;

  for (int kt = 0; kt < K; kt += BK) {
    // stage A,B tiles: 16B/lane direct global->LDS (wave-uniform LDS base + lane*16)
#pragma unroll
    for (int i = 0; i < 4; i++) {
      int idx = (i * 256 + tid) * 8;              // element index in 128x64 tile
      int r = idx >> 6, c = idx & 63;
      GLOBAL_TO_LDS16(Abase + (size_t)r * K + kt + c, As + (i * 256 + wid * 64) * 8);
    }
#pragma unroll
    for (int i = 0; i < 4; i++) {
      int idx = (i * 256 + tid) * 8;
      int r = idx >> 6, c = idx & 63;
      GLOBAL_TO_LDS16(Bbase + (size_t)r * K + kt + c, Bs + (i * 256 + wid * 64) * 8);
    }
    __syncthreads();  // compiler emits vmcnt(0) drain before barrier
#pragma unroll
    for (int kk = 0; kk < BK; kk += 32) {
      bf16x8 af[4], bfr[4];
#pragma unroll
      for (int i = 0; i < 4; i++)
        af[i] = *(const bf16x8*)(As + (wm + i * 16 + lr) * BK + kk + kq);
#pragma unroll
      for (int j = 0; j < 4; j++)
        bfr[j] = *(const bf16x8*)(Bs + (wn + j * 16 + lr) * BK + kk + kq);
#pragma unroll
      for (int i = 0; i < 4; i++)
#pragma unroll
        for (int j = 0; j < 4; j++)
          acc[i][j] = __builtin_amdgcn_mfma_f32_16x16x32_bf16(af[i], bfr[j], acc[i][j], 0, 0, 0);
    }
    __syncthreads();
  }

  // epilogue; C/D layout: col = lane&15, row = (lane>>4)*4 + reg  [m89-verified]
  int quad = (lane >> 4) * 4;
#pragma unroll
  for (int i = 0; i < 4; i++) {
#pragma unroll
    for (int r = 0; r < 4; r++) {
      int grow = m_start + wm + i * 16 + quad + r;
      if (grow < row_end) {
        if (EPI == 0) {
          size_t basei = (size_t)grow * N + nt * BN + wn + lr;
#pragma unroll
          for (int j = 0; j < 4; j++)
            Hout[basei + j * 16] = __float2bfloat16(gelu_tanh(acc[i][j][r]));
        } else {
          int tok = row_token[grow];
          float g = row_gate[grow];
          size_t basei = (size_t)tok * N + nt * BN + wn + lr;
#pragma unroll
          for (int j = 0; j < 4; j++)
            atomicAdd(out + basei + j * 16, g * acc[i][j][r]);
        }
      }
    }
  }
}

extern "C" void kernel_launch(void* const* d_in, const int* in_sizes, int n_in,
                              void* d_out, int out_size, void* d_ws, size_t ws_size,
                              hipStream_t stream) {
  (void)in_sizes; (void)n_in; (void)out_size; (void)ws_size;
  const float* x  = (const float*)d_in[0];
  const float* rw = (const float*)d_in[1];
  const float* w1 = (const float*)d_in[2];
  const float* w2 = (const float*)d_in[3];
  float* out = (float*)d_out;

  char* ws = (char*)d_ws;
  size_t off = 0;
  auto alloc = [&](size_t bytes) -> char* {
    off = (off + 255) & ~(size_t)255;
    char* p = ws + off;
    off += bytes;
    return p;
  };
  int*   counts    = (int*)alloc(NEXP * 4);
  int*   pair_e    = (int*)alloc((size_t)RTOT * 4);
  int*   pair_slot = (int*)alloc((size_t)RTOT * 4);
  float* pair_gate = (float*)alloc((size_t)RTOT * 4);
  int*   row_token = (int*)alloc((size_t)RTOT * 4);
  float* row_gate  = (float*)alloc((size_t)RTOT * 4);
  __hip_bfloat16* Xg  = (__hip_bfloat16*)alloc((size_t)RPAD * DDIM * 2);
  __hip_bfloat16* w1t = (__hip_bfloat16*)alloc((size_t)NEXP * DDIM * FDIM * 2);
  __hip_bfloat16* w2t = (__hip_bfloat16*)alloc((size_t)NEXP * DDIM * FDIM * 2);
  __hip_bfloat16* H   = (__hip_bfloat16*)alloc((size_t)RPAD * FDIM * 2);
  // total ws use: ~304 MB

  hipMemsetAsync(counts, 0, NEXP * 4, stream);
  hipMemsetAsync(out, 0, (size_t)T_TOK * DDIM * 4, stream);

  // w1 [E][D][F] -> w1t [E][F][D]; w2 [E][F][D] -> w2t [E][D][F]
  transpose_cast<<<NEXP * (DDIM / 64) * (FDIM / 64), 256, 0, stream>>>(w1, w1t, DDIM, FDIM);
  transpose_cast<<<NEXP * (FDIM / 64) * (DDIM / 64), 256, 0, stream>>>(w2, w2t, FDIM, DDIM);

  router_kernel<<<T_TOK / 4, 256, 0, stream>>>(x, rw, counts, pair_e, pair_slot, pair_gate);
  gather_kernel<<<RTOT, 256, 0, stream>>>(x, counts, pair_e, pair_slot, pair_gate, Xg, row_token, row_gate);

  moe_gemm<0><<<NEXP * (T_TOK / BM) * (FDIM / BN), 256, 0, stream>>>(
      Xg, w1t, H, nullptr, counts, nullptr, nullptr, DDIM, FDIM);
  moe_gemm<1><<<NEXP * (T_TOK / BM) * (DDIM / BN), 256, 0, stream>>>(
      H, w2t, nullptr, out, counts, row_token, row_gate, FDIM, DDIM);
}

// Round 2
// 944.354 us; speedup vs baseline: 1.2971x; 1.2971x over previous
//
#include <hip/hip_runtime.h>
#include <hip/hip_bf16.h>

// MoE top-2: T=8192 tokens, D=1024, F=4096, E=8.
// Pipeline: fused transpose-cast -> router -> gather -> GEMM1(gelu) -> GEMM2(gated P) -> combine.

#define T_TOK 8192
#define DDIM  1024
#define FDIM  4096
#define NEXP  8
#define RTOT  (T_TOK * 2)      // total assigned rows (top-2, always exactly 2T)
#define RPAD  (RTOT + 128)     // slack so tile staging can over-read harmlessly

#define BM 128
#define BN 128
#define BK 64

typedef __bf16 bf16x8 __attribute__((ext_vector_type(8)));
typedef float  f32x4  __attribute__((ext_vector_type(4)));

__device__ __forceinline__ float gelu_tanh(float x) {
  // 0.5x(1+tanh(u)) == x * sigmoid(2u); u = sqrt(2/pi)(x + 0.044715 x^3)
  float u = 0.7978845608028654f * (x + 0.044715f * x * x * x);
  return __fdividef(x, 1.f + __expf(-2.f * u));
}

#define GLOBAL_TO_LDS16(gp, lp)                                                   \
  __builtin_amdgcn_global_load_lds((const __attribute__((address_space(1))) void*)(gp), \
                                   (__attribute__((address_space(3))) void*)(lp), 16, 0, 0)

// ---------------- fused transpose+cast for w1 and w2 ----------------
// fp32 [E][Rr][Cc] -> bf16 [E][Cc][Rr]. float4 loads, 16B bf16 stores.
// LDS row stride 66 bf16: load-phase writes and store-phase column reads stay >=2-way (free/cheap).
__global__ __launch_bounds__(256) void transpose_cast_both(const float* __restrict__ w1,
                                                           const float* __restrict__ w2,
                                                           __hip_bfloat16* __restrict__ w1t,
                                                           __hip_bfloat16* __restrict__ w2t) {
  __shared__ __hip_bfloat16 tile[64 * 66];
  int bid = blockIdx.x;
  const float* in; __hip_bfloat16* outp; int Rr, Cc;
  if (bid < NEXP * 1024) { in = w1; outp = w1t; Rr = DDIM; Cc = FDIM; }
  else { bid -= NEXP * 1024; in = w2; outp = w2t; Rr = FDIM; Cc = DDIM; }
  int tilesC = Cc >> 6;
  int per = (Rr >> 6) * tilesC;  // == 1024
  int e = bid / per, rem = bid % per;
  int tr = rem / tilesC, tc = rem % tilesC;
  const float* ip = in + (size_t)e * Rr * Cc + (size_t)(tr * 64) * Cc + tc * 64;
  __hip_bfloat16* op = outp + (size_t)e * Rr * Cc + (size_t)(tc * 64) * Rr + tr * 64;
  int tid = threadIdx.x;
  int lrow = tid >> 4, lcol = (tid & 15) * 4;
#pragma unroll
  for (int p = 0; p < 4; p++) {
    int r = p * 16 + lrow;
    float4 v = *(const float4*)(ip + (size_t)r * Cc + lcol);
    tile[r * 66 + lcol + 0] = __float2bfloat16(v.x);
    tile[r * 66 + lcol + 1] = __float2bfloat16(v.y);
    tile[r * 66 + lcol + 2] = __float2bfloat16(v.z);
    tile[r * 66 + lcol + 3] = __float2bfloat16(v.w);
  }
  __syncthreads();
  int orow_l = tid >> 3, ocol = (tid & 7) * 8;
#pragma unroll
  for (int p = 0; p < 2; p++) {
    int orow = p * 32 + orow_l;  // output row == original column
    union { __hip_bfloat16 h[8]; uint4 u; } pk;
#pragma unroll
    for (int j = 0; j < 8; j++) pk.h[j] = tile[(ocol + j) * 66 + orow];
    *(uint4*)(op + (size_t)orow * Rr + ocol) = pk.u;
  }
}

// ---------------- router: logits -> top2 -> gates + slot assignment ----------------
__global__ __launch_bounds__(256) void router_kernel(const float* __restrict__ x,
                                                     const float* __restrict__ rw,
                                                     int* __restrict__ counts,
                                                     int* __restrict__ pair_e,
                                                     int* __restrict__ pair_slot,
                                                     float* __restrict__ pair_gate) {
  int lane = threadIdx.x & 63;
  int wid = threadIdx.x >> 6;
  int t = blockIdx.x * 4 + wid;  // one wave per token
  const float* xr = x + (size_t)t * DDIM;
  float acc[NEXP];
#pragma unroll
  for (int e = 0; e < NEXP; e++) acc[e] = 0.f;
  for (int d0 = lane * 4; d0 < DDIM; d0 += 256) {
    float4 xv = *(const float4*)(xr + d0);
    const float* r0 = rw + (size_t)d0 * NEXP;
#pragma unroll
    for (int e = 0; e < NEXP; e++)
      acc[e] += xv.x * r0[e] + xv.y * r0[NEXP + e] + xv.z * r0[2 * NEXP + e] + xv.w * r0[3 * NEXP + e];
  }
#pragma unroll
  for (int e = 0; e < NEXP; e++) {
#pragma unroll
    for (int m = 32; m > 0; m >>= 1) acc[e] += __shfl_xor(acc[e], m, 64);
  }
  if (lane == 0) {
    int e1 = 0; float l1 = acc[0];
    for (int e = 1; e < NEXP; e++) if (acc[e] > l1) { l1 = acc[e]; e1 = e; }
    int e2 = -1; float l2 = -1e30f;
    for (int e = 0; e < NEXP; e++) { if (e == e1) continue; if (acc[e] > l2) { l2 = acc[e]; e2 = e; } }
    // renormalized top-2 softmax == softmax over the two logits
    float g1 = 1.f / (1.f + __expf(l2 - l1));
    float g2 = 1.f - g1;
    int s1 = atomicAdd(&counts[e1], 1);
    int s2 = atomicAdd(&counts[e2], 1);
    pair_e[2 * t] = e1;     pair_slot[2 * t] = s1;     pair_gate[2 * t] = g1;
    pair_e[2 * t + 1] = e2; pair_slot[2 * t + 1] = s2; pair_gate[2 * t + 1] = g2;
  }
}

// ---------------- gather: x rows -> expert-compacted bf16 Xg ----------------
__global__ __launch_bounds__(256) void gather_kernel(const float* __restrict__ x,
                                                     const int* __restrict__ counts,
                                                     const int* __restrict__ pair_e,
                                                     const int* __restrict__ pair_slot,
                                                     const float* __restrict__ pair_gate,
                                                     __hip_bfloat16* __restrict__ Xg,
                                                     int* __restrict__ trow,
                                                     float* __restrict__ row_gate) {
  int p = blockIdx.x;
  int t = p >> 1;
  int e = pair_e[p];
  int base = 0;
#pragma unroll
  for (int i = 0; i < NEXP; i++) base += (i < e) ? counts[i] : 0;
  int row = base + pair_slot[p];
  const float* xr = x + (size_t)t * DDIM;
  __hip_bfloat16* dst = Xg + (size_t)row * DDIM;
  int i = threadIdx.x * 4;
  float4 v = *(const float4*)(xr + i);
  union { ushort4 u; __hip_bfloat16 h[4]; } o;
  o.h[0] = __float2bfloat16(v.x);
  o.h[1] = __float2bfloat16(v.y);
  o.h[2] = __float2bfloat16(v.z);
  o.h[3] = __float2bfloat16(v.w);
  *(ushort4*)(dst + i) = o.u;
  if (threadIdx.x == 0) { trow[p] = row; row_gate[row] = pair_gate[p]; }
}

// ---------------- tiled bf16 MFMA GEMM, per-expert row ranges ----------------
// A: bf16 [RPAD][K] (expert-compacted). Bw: bf16 [E][N][K].
// LDS tiles XOR-swizzled: slot (r,c) holds global chunk (r, c ^ (r&7)); fragment
// reads then spread over 8 distinct 4-bank groups (2-way aliasing only == free).
// EPI=0: Hout[row][N] = gelu(A@B) bf16.  EPI=1: Cout[row][N] = gate*(A@B) fp32.
template <int EPI>
__global__ __launch_bounds__(256) void moe_gemm(const __hip_bfloat16* __restrict__ A,
                                                const __hip_bfloat16* __restrict__ Bw,
                                                __hip_bfloat16* __restrict__ Hout,
                                                float* __restrict__ Cout,
                                                const int* __restrict__ counts,
                                                const float* __restrict__ row_gate,
                                                int K, int N) {
  const int MT = T_TOK / BM;  // worst-case m-tiles per expert
  const int NT = N / BN;
  int bid = blockIdx.x;
  int e = bid / (MT * NT);
  int rem = bid % (MT * NT);
  const int GM = 8;
  int width = GM * NT;
  int group = rem / width;
  int gm0 = group * GM;
  int gsize = (MT - gm0 < GM) ? (MT - gm0) : GM;
  int mt = gm0 + (rem % gsize);
  int nt = (rem % width) / gsize;

  int n_e = counts[e];
  if (mt * BM >= n_e) return;
  int row0 = 0;
  for (int i = 0; i < NEXP; i++) row0 += (i < e) ? counts[i] : 0;
  int m_start = row0 + mt * BM;
  int row_end = row0 + n_e;

  const __hip_bfloat16* Abase = A + (size_t)m_start * K;
  const __hip_bfloat16* Bbase = Bw + (size_t)e * N * K + (size_t)(nt * BN) * K;

  __shared__ alignas(16) __hip_bfloat16 As[BM * BK];
  __shared__ alignas(16) __hip_bfloat16 Bs[BN * BK];

  int tid = threadIdx.x;
  int lane = tid & 63, wid = tid >> 6;
  int wm = (wid >> 1) * 64, wn = (wid & 1) * 64;  // 2x2 wave grid, 64x64 each
  int lr = lane & 15;
  int kq8 = (lane >> 4);        // k-chunk index within 32-wide kk step

  f32x4 acc[4][4];
#pragma unroll
  for (int i = 0; i < 4; i++)
#pragma unroll
    for (int j = 0; j < 4; j++)
#pragma unroll
      for (int r = 0; r < 4; r++) acc[i][j][r] = 0.f;

  for (int kt = 0; kt < K; kt += BK) {
    // stage A,B tiles: 16B/lane direct global->LDS, source column XOR-swizzled
#pragma unroll
    for (int i = 0; i < 4; i++) {
      int q = i * 256 + tid;                  // chunk id in 128x64 tile (8 chunks/row)
      int r = q >> 3, c = (q & 7) ^ (r & 7);  // source chunk for this LDS slot
      GLOBAL_TO_LDS16(Abase + (size_t)r * K + kt + c * 8, As + (size_t)(i * 256 + wid * 64) * 8);
    }
#pragma unroll
    for (int i = 0; i < 4; i++) {
      int q = i * 256 + tid;
      int r = q >> 3, c = (q & 7) ^ (r & 7);
      GLOBAL_TO_LDS16(Bbase + (size_t)r * K + kt + c * 8, Bs + (size_t)(i * 256 + wid * 64) * 8);
    }
    __syncthreads();
#pragma unroll
    for (int kk = 0; kk < BK; kk += 32) {
      int kc = (kk >> 3) + kq8;  // chunk 0..7 along K
      bf16x8 af[4], bfr[4];
#pragma unroll
      for (int i = 0; i < 4; i++) {
        int R = wm + i * 16 + lr;
        af[i] = *(const bf16x8*)(As + R * BK + ((kc ^ (R & 7)) * 8));
      }
#pragma unroll
      for (int j = 0; j < 4; j++) {
        int R = wn + j * 16 + lr;
        bfr[j] = *(const bf16x8*)(Bs + R * BK + ((kc ^ (R & 7)) * 8));
      }
#pragma unroll
      for (int i = 0; i < 4; i++)
#pragma unroll
        for (int j = 0; j < 4; j++)
          acc[i][j] = __builtin_amdgcn_mfma_f32_16x16x32_bf16(af[i], bfr[j], acc[i][j], 0, 0, 0);
    }
    __syncthreads();
  }

  // epilogue; C/D layout: col = lane&15, row = (lane>>4)*4 + reg  [m89-verified]
  int quad = (lane >> 4) * 4;
#pragma unroll
  for (int i = 0; i < 4; i++) {
#pragma unroll
    for (int r = 0; r < 4; r++) {
      int grow = m_start + wm + i * 16 + quad + r;
      if (grow < row_end) {
        size_t basei = (size_t)grow * N + nt * BN + wn + lr;
        if (EPI == 0) {
#pragma unroll
          for (int j = 0; j < 4; j++)
            Hout[basei + j * 16] = __float2bfloat16(gelu_tanh(acc[i][j][r]));
        } else {
          float g = row_gate[grow];
#pragma unroll
          for (int j = 0; j < 4; j++)
            Cout[basei + j * 16] = g * acc[i][j][r];
        }
      }
    }
  }
}

// ---------------- combine: out[t] = P[row1] + P[row2] (gates pre-applied) ----------------
__global__ __launch_bounds__(256) void combine_kernel(const float* __restrict__ P,
                                                      const int* __restrict__ trow,
                                                      float* __restrict__ out) {
  int t = blockIdx.x;
  int r1 = trow[2 * t], r2 = trow[2 * t + 1];
  int d = threadIdx.x * 4;
  float4 a = *(const float4*)(P + (size_t)r1 * DDIM + d);
  float4 b = *(const float4*)(P + (size_t)r2 * DDIM + d);
  float4 o;
  o.x = a.x + b.x; o.y = a.y + b.y; o.z = a.z + b.z; o.w = a.w + b.w;
  *(float4*)(out + (size_t)t * DDIM + d) = o;
}

extern "C" void kernel_launch(void* const* d_in, const int* in_sizes, int n_in,
                              void* d_out, int out_size, void* d_ws, size_t ws_size,
                              hipStream_t stream) {
  (void)in_sizes; (void)n_in; (void)out_size; (void)ws_size;
  const float* x  = (const float*)d_in[0];
  const float* rw = (const float*)d_in[1];
  const float* w1 = (const float*)d_in[2];
  const float* w2 = (const float*)d_in[3];
  float* out = (float*)d_out;

  char* ws = (char*)d_ws;
  size_t off = 0;
  auto alloc = [&](size_t bytes) -> char* {
    off = (off + 255) & ~(size_t)255;
    char* p = ws + off;
    off += bytes;
    return p;
  };
  int*   counts    = (int*)alloc(NEXP * 4);
  int*   pair_e    = (int*)alloc((size_t)RTOT * 4);
  int*   pair_slot = (int*)alloc((size_t)RTOT * 4);
  float* pair_gate = (float*)alloc((size_t)RTOT * 4);
  int*   trow      = (int*)alloc((size_t)RTOT * 4);
  float* row_gate  = (float*)alloc((size_t)RTOT * 4);
  __hip_bfloat16* Xg  = (__hip_bfloat16*)alloc((size_t)RPAD * DDIM * 2);
  __hip_bfloat16* w1t = (__hip_bfloat16*)alloc((size_t)NEXP * DDIM * FDIM * 2);
  __hip_bfloat16* w2t = (__hip_bfloat16*)alloc((size_t)NEXP * DDIM * FDIM * 2);
  __hip_bfloat16* H   = (__hip_bfloat16*)alloc((size_t)RPAD * FDIM * 2);
  // P aliases w1t: w1t is dead after GEMM1; both are 67.1 MB. Every call rewrites
  // w1t (transpose) before GEMM1, and GEMM2 fully writes P before combine reads it.
  float* P = (float*)w1t;      // [RTOT][DDIM] fp32 gated partials

  hipMemsetAsync(counts, 0, NEXP * 4, stream);

  transpose_cast_both<<<2 * NEXP * 1024, 256, 0, stream>>>(w1, w2, w1t, w2t);
  router_kernel<<<T_TOK / 4, 256, 0, stream>>>(x, rw, counts, pair_e, pair_slot, pair_gate);
  gather_kernel<<<RTOT, 256, 0, stream>>>(x, counts, pair_e, pair_slot, pair_gate, Xg, trow, row_gate);

  moe_gemm<0><<<NEXP * (T_TOK / BM) * (FDIM / BN), 256, 0, stream>>>(
      Xg, w1t, H, nullptr, counts, nullptr, DDIM, FDIM);
  moe_gemm<1><<<NEXP * (T_TOK / BM) * (DDIM / BN), 256, 0, stream>>>(
      H, w2t, nullptr, P, counts, row_gate, FDIM, DDIM);
  combine_kernel<<<T_TOK, 256, 0, stream>>>(P, trow, out);
}